// Round 2
// baseline (418.077 us; speedup 1.0000x reference)
//
#include <hip/hip_runtime.h>

// MultiFeatureRNNModel: 2-layer tanh RNN (H1=5,H2=3), T=512, B=8192, F=16,
// final-step FC(3->1)+sigmoid.
//
// Producer/consumer wave pipeline, 256 blocks x 256 threads (1 block/CU):
//   waves 2,3: xproj = x @ W_ih1^T + bias1  -> LDS ring (B*T-parallel work)
//   wave 0:    layer-1 recurrence (serial in t) -> h1 ring
//   wave 1:    layer-2 recurrence (one chunk behind) + FC head
// Memory floor: 256 MiB x read ~= 42 us @ 6.3 TB/s. Target ~45-55 us.

namespace {

constexpr int kB  = 8192;
constexpr int kT  = 512;
constexpr int kF  = 16;
constexpr int kH1 = 5;
constexpr int kH2 = 3;

constexpr int SPB = 32;          // sequences per block
constexpr int C   = 16;          // timesteps per chunk
constexpr int NC  = kT / C;      // 32 chunks

__device__ __forceinline__ float fast_tanh(float v) {
    // tanh(v) = 1 - 2/(exp(2v)+1); saturates correctly at +-1.
    float e = __expf(v + v);
    return 1.0f - __fdividef(2.0f, e + 1.0f);
}

__device__ __forceinline__ void load_chunk(const float4* __restrict__ xs,
                                           int k, int plane, float4 nb[4][4]) {
#pragma unroll
    for (int i = 0; i < 4; ++i) {
        const int tg = k * C + plane + 4 * i;
#pragma unroll
        for (int q = 0; q < 4; ++q) nb[i][q] = xs[tg * 4 + q];
    }
}

__global__ __launch_bounds__(256) void rnn_pipe_kernel(
    const float* __restrict__ x,      // [B,T,F]
    const float* __restrict__ W_ih1,  // [H1,F]
    const float* __restrict__ W_hh1,  // [H1,H1]
    const float* __restrict__ b_ih1,  // [H1]
    const float* __restrict__ b_hh1,  // [H1]
    const float* __restrict__ W_ih2,  // [H2,H1]
    const float* __restrict__ W_hh2,  // [H2,H2]
    const float* __restrict__ b_ih2,  // [H2]
    const float* __restrict__ b_hh2,  // [H2]
    const float* __restrict__ W_fc,   // [1,H2]
    const float* __restrict__ b_fc,   // [1]
    float* __restrict__ out)          // [B]
{
    // rings: [buf][t][h][seq] -> consumer lane==seq hits distinct banks.
    __shared__ float xp [2][C][kH1][SPB];
    __shared__ float h1r[2][C][kH1][SPB];

    const int tid  = threadIdx.x;
    const int wave = tid >> 6;
    const int lane = tid & 63;
    const int s    = lane & 31;           // sequence slot within block
    const bool act = (lane < 32);

    if (wave >= 2) {
        // ---------------- PRODUCER (waves 2,3) ----------------
        const int plane = (wave - 2) * 2 + (lane >> 5);   // 0..3
        float w1[kH1][kF], bs1[kH1];
#pragma unroll
        for (int h = 0; h < kH1; ++h) {
            bs1[h] = b_ih1[h] + b_hh1[h];
#pragma unroll
            for (int f = 0; f < kF; ++f) w1[h][f] = W_ih1[h * kF + f];
        }
        const float4* xs = reinterpret_cast<const float4*>(x) +
                           (size_t)(blockIdx.x * SPB + s) * (kT * 4);

        float4 nb[4][4];
        load_chunk(xs, 0, plane, nb);     // prologue: chunk 0 in flight

        for (int k = 0; k < NC + 2; ++k) {
            if (k < NC) {
                const int buf = k & 1;
#pragma unroll
                for (int i = 0; i < 4; ++i) {
                    const int tl = plane + 4 * i;
                    const float xv[kF] = {
                        nb[i][0].x, nb[i][0].y, nb[i][0].z, nb[i][0].w,
                        nb[i][1].x, nb[i][1].y, nb[i][1].z, nb[i][1].w,
                        nb[i][2].x, nb[i][2].y, nb[i][2].z, nb[i][2].w,
                        nb[i][3].x, nb[i][3].y, nb[i][3].z, nb[i][3].w};
#pragma unroll
                    for (int h = 0; h < kH1; ++h) {
                        float acc = bs1[h];
#pragma unroll
                        for (int f = 0; f < kF; ++f)
                            acc = fmaf(xv[f], w1[h][f], acc);
                        xp[buf][tl][h][s] = acc;
                    }
                }
                // issue next chunk's loads; latency hides under barrier wait
                if (k + 1 < NC) load_chunk(xs, k + 1, plane, nb);
            }
            __syncthreads();
        }
    } else if (wave == 0) {
        // ---------------- LAYER-1 RECURRENCE (wave 0) ----------------
        float whh1[kH1][kH1];
#pragma unroll
        for (int h = 0; h < kH1; ++h)
#pragma unroll
            for (int j = 0; j < kH1; ++j) whh1[h][j] = W_hh1[h * kH1 + j];

        float h1[kH1] = {0.f, 0.f, 0.f, 0.f, 0.f};

        for (int k = 0; k < NC + 2; ++k) {
            if (k >= 1 && k <= NC && act) {
                const int buf = (k - 1) & 1;
#pragma unroll 4
                for (int t = 0; t < C; ++t) {
                    float a[kH1];
#pragma unroll
                    for (int h = 0; h < kH1; ++h) {
                        float acc = xp[buf][t][h][s];   // includes bias1
#pragma unroll
                        for (int j = 0; j < kH1; ++j)
                            acc = fmaf(h1[j], whh1[h][j], acc);
                        a[h] = acc;
                    }
#pragma unroll
                    for (int h = 0; h < kH1; ++h) {
                        h1[h] = fast_tanh(a[h]);
                        h1r[buf][t][h][s] = h1[h];
                    }
                }
            }
            __syncthreads();
        }
    } else {
        // ---------------- LAYER-2 RECURRENCE + HEAD (wave 1) ----------------
        float wih2[kH2][kH1], whh2[kH2][kH2], bs2[kH2], wfc[kH2];
#pragma unroll
        for (int m = 0; m < kH2; ++m) {
            bs2[m] = b_ih2[m] + b_hh2[m];
            wfc[m] = W_fc[m];
#pragma unroll
            for (int j = 0; j < kH1; ++j) wih2[m][j] = W_ih2[m * kH1 + j];
#pragma unroll
            for (int j = 0; j < kH2; ++j) whh2[m][j] = W_hh2[m * kH2 + j];
        }
        const float bfc = b_fc[0];

        float h2[kH2] = {0.f, 0.f, 0.f};

        for (int k = 0; k < NC + 2; ++k) {
            if (k >= 2 && act) {
                const int buf = (k - 2) & 1;
#pragma unroll 4
                for (int t = 0; t < C; ++t) {
                    float h1v[kH1];
#pragma unroll
                    for (int j = 0; j < kH1; ++j) h1v[j] = h1r[buf][t][j][s];
                    float c[kH2];
#pragma unroll
                    for (int m = 0; m < kH2; ++m) {
                        float acc = bs2[m];
#pragma unroll
                        for (int j = 0; j < kH1; ++j)
                            acc = fmaf(h1v[j], wih2[m][j], acc);
#pragma unroll
                        for (int j = 0; j < kH2; ++j)
                            acc = fmaf(h2[j], whh2[m][j], acc);
                        c[m] = acc;
                    }
#pragma unroll
                    for (int m = 0; m < kH2; ++m) h2[m] = fast_tanh(c[m]);
                }
            }
            __syncthreads();
        }

        if (act) {
            float z = bfc;
#pragma unroll
            for (int m = 0; m < kH2; ++m) z = fmaf(h2[m], wfc[m], z);
            out[blockIdx.x * SPB + s] =
                __fdividef(1.0f, 1.0f + __expf(-z));
        }
    }
}

}  // namespace

extern "C" void kernel_launch(void* const* d_in, const int* in_sizes, int n_in,
                              void* d_out, int out_size, void* d_ws, size_t ws_size,
                              hipStream_t stream) {
    const float* x     = (const float*)d_in[0];
    const float* W_ih1 = (const float*)d_in[1];
    const float* W_hh1 = (const float*)d_in[2];
    const float* b_ih1 = (const float*)d_in[3];
    const float* b_hh1 = (const float*)d_in[4];
    const float* W_ih2 = (const float*)d_in[5];
    const float* W_hh2 = (const float*)d_in[6];
    const float* b_ih2 = (const float*)d_in[7];
    const float* b_hh2 = (const float*)d_in[8];
    const float* W_fc  = (const float*)d_in[9];
    const float* b_fc  = (const float*)d_in[10];
    float* out = (float*)d_out;

    dim3 grid(kB / SPB), block(256);   // 256 blocks -> 1 per CU
    rnn_pipe_kernel<<<grid, block, 0, stream>>>(
        x, W_ih1, W_hh1, b_ih1, b_hh1, W_ih2, W_hh2, b_ih2, b_hh2, W_fc, b_fc,
        out);
}